// Round 1
// baseline (42.688 us; speedup 1.0000x reference)
//
#include <hip/hip_runtime.h>

// AdaptiveVectorQuantizer on MI355X (gfx950).
// Shapes (fixed by setup_inputs): input (2,16,64,64,64) fp32 -> NB=32 images,
// C=D=64 channels, HW=4096 positions/image. codebook (16,64), prev (16,64),
// num_active_vectors=16 -> n_levels=4, nv per level = {2,4,8,16}.
// Output: quantized (4,32,64,64,64) fp32, losses (4,), codebook[:16] (16,64).

namespace {

constexpr int D     = 64;
constexpr int P     = 16;
constexpr int NLEV  = 4;
constexpr int BLOCK = 256;
constexpr int NPOS  = 32 * 4096;      // 131072 positions
constexpr int NBLK  = NPOS / BLOCK;   // 512 blocks

__global__ __launch_bounds__(BLOCK) void avq_main(
    const float* __restrict__ in,
    const float* __restrict__ cb,
    float* __restrict__ out,
    float* __restrict__ partial)
{
  // +1 pad on the row: epilogue gathers cb_s[idx][c] with per-lane idx;
  // unpadded stride 64 floats => all lanes hit bank (c&31) (16-way conflict).
  // stride 65 => bank (idx+c)&31, distinct per distinct idx => conflict-free.
  __shared__ float cb_s[P][D + 1];
  __shared__ float cb2_s[P];
  __shared__ float wred[4 * NLEV];

  const int tid = threadIdx.x;
  for (int i = tid; i < P * D; i += BLOCK)
    cb_s[i >> 6][i & 63] = cb[i];
  __syncthreads();
  if (tid < P) {
    float s = 0.f;
    #pragma unroll
    for (int c = 0; c < D; ++c) { const float v = cb_s[tid][c]; s = fmaf(v, v, s); }
    cb2_s[tid] = s;
  }
  __syncthreads();

  const int p  = blockIdx.x * BLOCK + tid;   // position index
  const int n  = p >> 12;                    // image (block never straddles n)
  const int hw = p & 4095;
  const float* __restrict__ src = in + (n << 18) + hw;   // stride 4096 over c

  float dot[P];
  #pragma unroll
  for (int q = 0; q < P; ++q) dot[q] = 0.f;
  float x2 = 0.f;

  // Wave reads 256B contiguous per channel plane -> coalesced.
  #pragma unroll
  for (int c = 0; c < D; ++c) {
    const float xv = src[c << 12];
    x2 = fmaf(xv, xv, x2);
    #pragma unroll
    for (int q = 0; q < P; ++q) dot[q] = fmaf(xv, cb_s[q][c], dot[q]);
  }

  // rel = cb^2 - 2*dot ; x2 is a common offset -> drop it for argmin
  float rel[P];
  #pragma unroll
  for (int q = 0; q < P; ++q) rel[q] = fmaf(-2.f, dot[q], cb2_s[q]);

  // Prefix argmins (strict < keeps jnp.argmin first-min tie-break).
  int   idx[NLEV];
  float err[NLEV];   // min distance == sum_c (q-x)^2 for this position
  {
    int bi = 0; float bv = rel[0];
    if (rel[1] < bv) { bv = rel[1]; bi = 1; }
    idx[0] = bi; err[0] = x2 + bv;
    #pragma unroll
    for (int q = 2; q < 4; ++q)  if (rel[q] < bv) { bv = rel[q]; bi = q; }
    idx[1] = bi; err[1] = x2 + bv;
    #pragma unroll
    for (int q = 4; q < 8; ++q)  if (rel[q] < bv) { bv = rel[q]; bi = q; }
    idx[2] = bi; err[2] = x2 + bv;
    #pragma unroll
    for (int q = 8; q < 16; ++q) if (rel[q] < bv) { bv = rel[q]; bi = q; }
    idx[3] = bi; err[3] = x2 + bv;
  }

  // Quantized output: out[l][n][c][hw] = cb[idx_l][c]; coalesced 256B/wave.
  float* __restrict__ dstbase = out + (n << 18) + hw;
  #pragma unroll
  for (int l = 0; l < NLEV; ++l) {
    const float* __restrict__ row = cb_s[idx[l]];
    float* __restrict__ dst = dstbase + (l << 23);
    #pragma unroll
    for (int c = 0; c < D; ++c) dst[c << 12] = row[c];
  }

  // Deterministic per-block loss partials (no float atomics).
  const int lane = tid & 63, wv = tid >> 6;
  #pragma unroll
  for (int l = 0; l < NLEV; ++l) {
    float v = err[l];
    #pragma unroll
    for (int off = 32; off > 0; off >>= 1) v += __shfl_down(v, off, 64);
    if (lane == 0) wred[wv * NLEV + l] = v;
  }
  __syncthreads();
  if (tid < NLEV) {
    partial[blockIdx.x * NLEV + tid] =
        wred[0 * NLEV + tid] + wred[1 * NLEV + tid] +
        wred[2 * NLEV + tid] + wred[3 * NLEV + tid];
  }
}

__device__ inline float block_sum256(float v, float* sbuf, int tid) {
  #pragma unroll
  for (int off = 32; off > 0; off >>= 1) v += __shfl_down(v, off, 64);
  __syncthreads();
  if ((tid & 63) == 0) sbuf[tid >> 6] = v;
  __syncthreads();
  const float r = sbuf[0] + sbuf[1] + sbuf[2] + sbuf[3];
  __syncthreads();
  return r;
}

__global__ __launch_bounds__(BLOCK) void avq_final(
    const float* __restrict__ partial,
    const float* __restrict__ cb,
    const float* __restrict__ prev,
    float* __restrict__ out)
{
  __shared__ float sbuf[4];
  const int tid = threadIdx.x;
  float* __restrict__ losses = out + (NLEV << 23);   // 4*32*64*4096 = 33554432
  float* __restrict__ cbout  = losses + NLEV;

  // codebook[:16] passthrough
  for (int i = tid; i < P * D; i += BLOCK) cbout[i] = cb[i];

  // Reduce the 512x4 block partials.
  float s0 = 0.f, s1 = 0.f, s2 = 0.f, s3 = 0.f;
  for (int b = tid; b < NBLK; b += BLOCK) {
    s0 += partial[b * NLEV + 0];
    s1 += partial[b * NLEV + 1];
    s2 += partial[b * NLEV + 2];
    s3 += partial[b * NLEV + 3];
  }

  // Proximity terms: mean((prev[:nv/2]-cb[:nv/2])^2), nv/2 = {2,4,8} rows.
  float p1 = 0.f, p2 = 0.f, p3 = 0.f;
  for (int e = tid; e < 8 * D; e += BLOCK) {
    const float dlt = prev[e] - cb[e];
    const float d2  = dlt * dlt;
    const int   r   = e >> 6;
    if (r < 2) p1 += d2;
    if (r < 4) p2 += d2;
    p3 += d2;
  }

  s0 = block_sum256(s0, sbuf, tid);
  s1 = block_sum256(s1, sbuf, tid);
  s2 = block_sum256(s2, sbuf, tid);
  s3 = block_sum256(s3, sbuf, tid);
  p1 = block_sum256(p1, sbuf, tid);
  p2 = block_sum256(p2, sbuf, tid);
  p3 = block_sum256(p3, sbuf, tid);

  if (tid == 0) {
    const float inv = 1.0f / 8388608.0f;               // 1/(M*D)
    const float ql0 = s0 * inv, ql1 = s1 * inv, ql2 = s2 * inv, ql3 = s3 * inv;
    // level 0,1: + COMMITMENT_W * align_loss (== quant_loss numerically)
    // level>=1: + level * PROXIMITY_W * prox_mean
    losses[0] = ql0 + 0.1f * ql0;
    losses[1] = ql1 + 0.1f * ql1 + 1.0f * 0.33f * (p1 * (1.0f / 128.0f));
    losses[2] = ql2 + 2.0f * 0.33f * (p2 * (1.0f / 256.0f));
    losses[3] = ql3 + 3.0f * 0.33f * (p3 * (1.0f / 512.0f));
  }
}

}  // namespace

extern "C" void kernel_launch(void* const* d_in, const int* in_sizes, int n_in,
                              void* d_out, int out_size, void* d_ws, size_t ws_size,
                              hipStream_t stream) {
  const float* in   = (const float*)d_in[0];
  const float* cb   = (const float*)d_in[1];
  const float* prev = (const float*)d_in[2];
  // d_in[3] = num_active_vectors (always 16 for this problem -> 4 levels)
  float* out     = (float*)d_out;
  float* partial = (float*)d_ws;   // NBLK*NLEV floats = 8 KiB scratch

  avq_main<<<NBLK, BLOCK, 0, stream>>>(in, cb, out, partial);
  avq_final<<<1, BLOCK, 0, stream>>>(partial, cb, prev, out);
}